// Round 1
// baseline (639.924 us; speedup 1.0000x reference)
//
#include <hip/hip_runtime.h>
#include <stdint.h>

// ---------------------------------------------------------------------------
// FeatureMapTransformer: dual cross-attention (rd / dr paths), B=2, C=512,
// H=W=64 -> N=M=4096.
//   Qt[n][c] = (Wq X)^T, Kt[m][c] = (Wk X)^T, V[c][m] = Wv X   (bf16)
//   Tt[n][m] = sum_c Kt[m][c] Qt[n][c]                          (bf16)
//   P[m][n]  = softmax over n of T row m  -> stored Pt[n][m] in place
//   O[c][n]  = sum_m V[c][m] Pt[n][m];  out = relu(gamma*O + resid)
// All GEMMs: bf16 MFMA 16x16x32, 128x128 block tile, 4 waves of 64x64.
// ---------------------------------------------------------------------------

typedef __attribute__((ext_vector_type(8))) __bf16 bf16x8;
typedef __attribute__((ext_vector_type(4))) float f32x4;
typedef __attribute__((ext_vector_type(4))) unsigned short us4;

#define LDS_STRIDE 40  // 32 + 8 pad: keeps 16B alignment, 2-way conflicts only

__device__ __forceinline__ unsigned short f2bf(float f) {
  union { float f; unsigned u; } v; v.f = f;
  unsigned r = v.u + 0x7FFFu + ((v.u >> 16) & 1u);
  return (unsigned short)(r >> 16);
}
__device__ __forceinline__ float bf2f(unsigned short b) {
  union { unsigned u; float f; } v; v.u = ((unsigned)b) << 16;
  return v.f;
}

// Core: C[128x128 at (rowbase,colbase)] += A[row][k] * B[col][k]^T
// A: [rows][K] row-major (lda), B: [cols][K] row-major (ldb) -- both K-contig.
__device__ __forceinline__ void gemm_core(
    const unsigned short* __restrict__ Ag, const unsigned short* __restrict__ Bg,
    int K, int lda, int ldb, int rowbase, int colbase,
    f32x4 (&acc)[4][4], unsigned short* Al, unsigned short* Bl) {
  const int tid = threadIdx.x;
  const int w = tid >> 6, lane = tid & 63;
  const int quad = lane >> 4, l16 = lane & 15;
  const int wm = (w >> 1) << 6, wn = (w & 1) << 6;

  for (int k0 = 0; k0 < K; k0 += 32) {
#pragma unroll
    for (int t = 0; t < 2; ++t) {
      int cid = (t << 8) + tid;
      int row = cid >> 2;
      int kc = (cid & 3) << 3;
      *(int4*)(Al + row * LDS_STRIDE + kc) =
          *(const int4*)(Ag + (size_t)(rowbase + row) * lda + (k0 + kc));
      *(int4*)(Bl + row * LDS_STRIDE + kc) =
          *(const int4*)(Bg + (size_t)(colbase + row) * ldb + (k0 + kc));
    }
    __syncthreads();
    bf16x8 af[4], bfr[4];
#pragma unroll
    for (int i = 0; i < 4; ++i)
      af[i] = *(const bf16x8*)(Al + (wm + (i << 4) + l16) * LDS_STRIDE + (quad << 3));
#pragma unroll
    for (int j = 0; j < 4; ++j)
      bfr[j] = *(const bf16x8*)(Bl + (wn + (j << 4) + l16) * LDS_STRIDE + (quad << 3));
#pragma unroll
    for (int i = 0; i < 4; ++i)
#pragma unroll
      for (int j = 0; j < 4; ++j)
        acc[i][j] = __builtin_amdgcn_mfma_f32_16x16x32_bf16(af[i], bfr[j], acc[i][j], 0, 0, 0);
    __syncthreads();
  }
}

// ---------------- weight fp32 -> bf16 -----------------------------------
struct WArgs { const float* src[6]; unsigned short* dst[6]; };
__global__ __launch_bounds__(256) void k_cvtw(WArgs a) {
  int z = blockIdx.y;
  int i = blockIdx.x * 256 + threadIdx.x;  // 512*512 = 262144 = 1024 blocks
  a.dst[z][i] = f2bf(a.src[z][i]);
}

// ---------------- transpose+convert: x[b][c][n] f32 -> Xt[b][n][c] bf16 --
__global__ __launch_bounds__(256) void k_tcvt(const float* __restrict__ src,
                                              unsigned short* __restrict__ dst) {
  __shared__ float tile[32][33];
  int n0 = blockIdx.x << 5;   // spatial
  int r0 = blockIdx.y << 5;   // global row = b*512 + c
  int tx = threadIdx.x & 31, ty = threadIdx.x >> 5;  // 32 x 8
#pragma unroll
  for (int i = 0; i < 4; ++i)
    tile[ty * 4 + i][tx] = src[(size_t)(r0 + ty * 4 + i) * 4096 + n0 + tx];
  __syncthreads();
  int b = r0 >> 9, c0 = r0 & 511;
#pragma unroll
  for (int i = 0; i < 4; ++i) {
    int nn = ty * 4 + i;
    dst[(size_t)b * (4096 * 512) + (size_t)(n0 + nn) * 512 + c0 + tx] =
        f2bf(tile[tx][nn]);
  }
}

// ---------------- conv1x1 GEMMs: Y[o][n] = W[o][c] Xt[n][c]^T + bias -----
struct ConvArgs {
  const unsigned short* W[12];
  const unsigned short* X[12];
  const float* bias[12];
  unsigned short* out[12];
  int trans[12];  // 1: store out[n][o] (Q,K) ; 0: store out[o][n] (V)
};
__global__ __launch_bounds__(256) void k_conv(ConvArgs a) {
  __shared__ unsigned short Al[128 * LDS_STRIDE], Bl[128 * LDS_STRIDE];
  int z = blockIdx.z;
  int rowbase = blockIdx.y << 7, colbase = blockIdx.x << 7;
  f32x4 acc[4][4];
#pragma unroll
  for (int i = 0; i < 4; ++i)
#pragma unroll
    for (int j = 0; j < 4; ++j) acc[i][j] = (f32x4){0.f, 0.f, 0.f, 0.f};
  gemm_core(a.W[z], a.X[z], 512, 512, 512, rowbase, colbase, acc, Al, Bl);

  const int tid = threadIdx.x, w = tid >> 6, lane = tid & 63;
  const int quad = lane >> 4, l16 = lane & 15;
  const int wm = (w >> 1) << 6, wn = (w & 1) << 6;
  const float* bias = a.bias[z];
  unsigned short* out = a.out[z];
  if (a.trans[z]) {
#pragma unroll
    for (int i = 0; i < 4; ++i) {
      int o0 = rowbase + wm + (i << 4) + (quad << 2);
      float b0 = bias[o0], b1 = bias[o0 + 1], b2 = bias[o0 + 2], b3 = bias[o0 + 3];
#pragma unroll
      for (int j = 0; j < 4; ++j) {
        int n = colbase + wn + (j << 4) + l16;
        us4 v;
        v.x = f2bf(acc[i][j].x + b0);
        v.y = f2bf(acc[i][j].y + b1);
        v.z = f2bf(acc[i][j].z + b2);
        v.w = f2bf(acc[i][j].w + b3);
        *(us4*)(out + (size_t)n * 512 + o0) = v;
      }
    }
  } else {
#pragma unroll
    for (int i = 0; i < 4; ++i) {
      int o0 = rowbase + wm + (i << 4) + (quad << 2);
      float b0 = bias[o0], b1 = bias[o0 + 1], b2 = bias[o0 + 2], b3 = bias[o0 + 3];
#pragma unroll
      for (int j = 0; j < 4; ++j) {
        int n = colbase + wn + (j << 4) + l16;
        out[(size_t)(o0 + 0) * 4096 + n] = f2bf(acc[i][j].x + b0);
        out[(size_t)(o0 + 1) * 4096 + n] = f2bf(acc[i][j].y + b1);
        out[(size_t)(o0 + 2) * 4096 + n] = f2bf(acc[i][j].z + b2);
        out[(size_t)(o0 + 3) * 4096 + n] = f2bf(acc[i][j].w + b3);
      }
    }
  }
}

// ---------------- T = K^T Q : Tt[n][m] bf16 ------------------------------
struct QKArgs { const unsigned short* A[4]; const unsigned short* B[4]; unsigned short* T[4]; };
__global__ __launch_bounds__(256) void k_qk(QKArgs a) {
  __shared__ unsigned short Al[128 * LDS_STRIDE], Bl[128 * LDS_STRIDE];
  int z = blockIdx.z;
  int rowbase = blockIdx.y << 7;  // m
  int colbase = blockIdx.x << 7;  // n
  f32x4 acc[4][4];
#pragma unroll
  for (int i = 0; i < 4; ++i)
#pragma unroll
    for (int j = 0; j < 4; ++j) acc[i][j] = (f32x4){0.f, 0.f, 0.f, 0.f};
  gemm_core(a.A[z], a.B[z], 512, 512, 512, rowbase, colbase, acc, Al, Bl);

  const int tid = threadIdx.x, w = tid >> 6, lane = tid & 63;
  const int quad = lane >> 4, l16 = lane & 15;
  const int wm = (w >> 1) << 6, wn = (w & 1) << 6;
  unsigned short* T = a.T[z];
#pragma unroll
  for (int i = 0; i < 4; ++i) {
    int m0 = rowbase + wm + (i << 4) + (quad << 2);
#pragma unroll
    for (int j = 0; j < 4; ++j) {
      int n = colbase + wn + (j << 4) + l16;
      us4 v;
      v.x = f2bf(acc[i][j].x);
      v.y = f2bf(acc[i][j].y);
      v.z = f2bf(acc[i][j].z);
      v.w = f2bf(acc[i][j].w);
      *(us4*)(T + (size_t)n * 4096 + m0) = v;
    }
  }
}

// ---------------- softmax stats over n per column m ----------------------
__global__ __launch_bounds__(256) void k_stats1(const unsigned short* __restrict__ T,
                                                float* __restrict__ pmx,
                                                float* __restrict__ pz) {
  int m = (blockIdx.x << 8) + threadIdx.x;
  int z = blockIdx.z;
  const unsigned short* Tz =
      T + (size_t)z * 4096 * 4096 + (size_t)(blockIdx.y * 512) * 4096 + m;
  float mx = -1e30f, s = 0.f;
  for (int n = 0; n < 512; ++n) {
    float v = bf2f(Tz[(size_t)n * 4096]);
    if (v > mx) { s = s * __expf(mx - v) + 1.f; mx = v; }
    else s += __expf(v - mx);
  }
  int idx = ((z << 3) + blockIdx.y) * 4096 + m;
  pmx[idx] = mx;
  pz[idx] = s;
}

__global__ __launch_bounds__(256) void k_stats2(const float* __restrict__ pmx,
                                                const float* __restrict__ pz,
                                                float* __restrict__ mxo,
                                                float* __restrict__ rzo) {
  int m = (blockIdx.x << 8) + threadIdx.x;
  int z = blockIdx.y;
  float M = -1e30f;
#pragma unroll
  for (int c = 0; c < 8; ++c) M = fmaxf(M, pmx[((z << 3) + c) * 4096 + m]);
  float S = 0.f;
#pragma unroll
  for (int c = 0; c < 8; ++c)
    S += pz[((z << 3) + c) * 4096 + m] * __expf(pmx[((z << 3) + c) * 4096 + m] - M);
  mxo[z * 4096 + m] = M;
  rzo[z * 4096 + m] = 1.f / S;
}

// ---------------- Pt[n][m] = exp(Tt-mx[m])*rz[m], in place ---------------
__global__ __launch_bounds__(256) void k_pwrite(unsigned short* __restrict__ T,
                                                const float* __restrict__ mx,
                                                const float* __restrict__ rz) {
  unsigned gid = blockIdx.x * 256 + threadIdx.x;  // 8 elems each
  int z = gid >> 21;
  unsigned rem = gid & 0x1FFFFFu;
  int n = rem >> 9;
  int m0 = (rem & 511) << 3;
  unsigned short* p = T + (size_t)z * 16777216 + (size_t)n * 4096 + m0;
  int4 raw = *(const int4*)p;
  unsigned short* u = (unsigned short*)&raw;
  const float* mxp = mx + z * 4096 + m0;
  const float* rzp = rz + z * 4096 + m0;
#pragma unroll
  for (int j = 0; j < 8; ++j)
    u[j] = f2bf(__expf(bf2f(u[j]) - mxp[j]) * rzp[j]);
  *(int4*)p = raw;
}

// ---------------- O = V * P, epilogue relu(gamma*O + resid) --------------
struct PVArgs {
  const unsigned short* V[4];
  const unsigned short* P[4];
  const float* resid[4];
  const float* gamma[4];
  float* out[4];
};
__global__ __launch_bounds__(256) void k_pv(PVArgs a) {
  __shared__ unsigned short Al[128 * LDS_STRIDE], Bl[128 * LDS_STRIDE];
  int z = blockIdx.z;
  int rowbase = blockIdx.y << 7;  // c
  int colbase = blockIdx.x << 7;  // n
  f32x4 acc[4][4];
#pragma unroll
  for (int i = 0; i < 4; ++i)
#pragma unroll
    for (int j = 0; j < 4; ++j) acc[i][j] = (f32x4){0.f, 0.f, 0.f, 0.f};
  gemm_core(a.V[z], a.P[z], 4096, 4096, 4096, rowbase, colbase, acc, Al, Bl);

  const int tid = threadIdx.x, w = tid >> 6, lane = tid & 63;
  const int quad = lane >> 4, l16 = lane & 15;
  const int wm = (w >> 1) << 6, wn = (w & 1) << 6;
  float g = a.gamma[z][0];
  const float* R = a.resid[z];
  float* O = a.out[z];
#pragma unroll
  for (int i = 0; i < 4; ++i) {
    int c0 = rowbase + wm + (i << 4) + (quad << 2);
#pragma unroll
    for (int j = 0; j < 4; ++j) {
      int n = colbase + wn + (j << 4) + l16;
      O[(size_t)(c0 + 0) * 4096 + n] = fmaxf(g * acc[i][j].x + R[(size_t)(c0 + 0) * 4096 + n], 0.f);
      O[(size_t)(c0 + 1) * 4096 + n] = fmaxf(g * acc[i][j].y + R[(size_t)(c0 + 1) * 4096 + n], 0.f);
      O[(size_t)(c0 + 2) * 4096 + n] = fmaxf(g * acc[i][j].z + R[(size_t)(c0 + 2) * 4096 + n], 0.f);
      O[(size_t)(c0 + 3) * 4096 + n] = fmaxf(g * acc[i][j].w + R[(size_t)(c0 + 3) * 4096 + n], 0.f);
    }
  }
}

// ---------------------------------------------------------------------------
extern "C" void kernel_launch(void* const* d_in, const int* in_sizes, int n_in,
                              void* d_out, int out_size, void* d_ws, size_t ws_size,
                              hipStream_t stream) {
  char* ws = (char*)d_ws;
  // workspace layout (bytes):
  unsigned short* wb  = (unsigned short*)(ws);              //  6 x 512x512 bf16 =   3,145,728
  unsigned short* xt  = (unsigned short*)(ws + 3145728);    //  4 x [2][4096][512] =33,554,432
  unsigned short* qkv = (unsigned short*)(ws + 36700160);   // 12 x [4096x512]   = 50,331,648
  unsigned short* tt  = (unsigned short*)(ws + 87031808);   //  4 x [4096x4096]  =134,217,728
  float* pmx = (float*)(ws + 221249536);                    // 4*8*4096 f32
  float* pz  = (float*)(ws + 221773824);
  float* mx  = (float*)(ws + 222298112);                    // 4*4096 f32
  float* rz  = (float*)(ws + 222363648);                    // total ~212.2 MB

  // 1. weights -> bf16
  WArgs wa;
  for (int i = 0; i < 6; ++i) {
    wa.src[i] = (const float*)d_in[4 + 2 * i];
    wa.dst[i] = wb + (size_t)i * 262144;
  }
  k_cvtw<<<dim3(1024, 6), 256, 0, stream>>>(wa);

  // 2. feature maps -> transposed bf16 Xt[b][n][c]
  for (int ai = 0; ai < 4; ++ai)
    k_tcvt<<<dim3(128, 32), 256, 0, stream>>>((const float*)d_in[ai],
                                              xt + (size_t)ai * 4194304);

  // 3. six convs x two batches
  // conv order: q_rd, k_rd, v_rd, q_dr, k_dr, v_dr
  const int srcArr[6] = {2, 0, 3, 3, 1, 1};  // x_vis_p, visSegF, x_ir_p, x_ir_p, irSegF, irSegF
  const int trans[6] = {1, 1, 0, 1, 1, 0};   // Q,K transposed; V normal
  ConvArgs ca;
  for (int ci = 0; ci < 6; ++ci)
    for (int b = 0; b < 2; ++b) {
      int z = ci * 2 + b;
      ca.W[z] = wb + (size_t)ci * 262144;
      ca.X[z] = xt + (size_t)srcArr[ci] * 4194304 + (size_t)b * 2097152;
      ca.bias[z] = (const float*)d_in[5 + 2 * ci];
      ca.out[z] = qkv + (size_t)z * 2097152;
      ca.trans[z] = trans[ci];
    }
  k_conv<<<dim3(32, 4, 12), 256, 0, stream>>>(ca);

  // 4. Tt[n][m] = K^T Q   (z = path*2 + b)
  QKArgs qa;
  for (int path = 0; path < 2; ++path)
    for (int b = 0; b < 2; ++b) {
      int z = path * 2 + b;
      qa.A[z] = qkv + (size_t)((path * 3 + 1) * 2 + b) * 2097152;  // Kt
      qa.B[z] = qkv + (size_t)((path * 3 + 0) * 2 + b) * 2097152;  // Qt
      qa.T[z] = tt + (size_t)z * 16777216;
    }
  k_qk<<<dim3(32, 32, 4), 256, 0, stream>>>(qa);

  // 5-6. per-m softmax stats (reduce over n)
  k_stats1<<<dim3(16, 8, 4), 256, 0, stream>>>(tt, pmx, pz);
  k_stats2<<<dim3(16, 4), 256, 0, stream>>>(pmx, pz, mx, rz);

  // 7. P in place
  k_pwrite<<<dim3(32768), 256, 0, stream>>>(tt, mx, rz);

  // 8. O = V P + fused epilogue
  PVArgs pa;
  const float* resid_src[2] = {(const float*)d_in[2], (const float*)d_in[3]};
  const float* gsrc[2] = {(const float*)d_in[16], (const float*)d_in[17]};
  for (int path = 0; path < 2; ++path)
    for (int b = 0; b < 2; ++b) {
      int z = path * 2 + b;
      pa.V[z] = qkv + (size_t)((path * 3 + 2) * 2 + b) * 2097152;
      pa.P[z] = tt + (size_t)z * 16777216;
      pa.resid[z] = resid_src[path] + (size_t)b * 2097152;
      pa.gamma[z] = gsrc[path];
      pa.out[z] = (float*)d_out + (size_t)path * 4194304 + (size_t)b * 2097152;
    }
  k_pv<<<dim3(32, 4, 4), 256, 0, stream>>>(pa);
}

// Round 2
// 535.105 us; speedup vs baseline: 1.1959x; 1.1959x over previous
//
#include <hip/hip_runtime.h>
#include <stdint.h>

// ---------------------------------------------------------------------------
// FeatureMapTransformer: dual cross-attention (rd / dr paths), B=2, C=512,
// H=W=64 -> N=M=4096.
//   Qt[n][c], Kt[m][c] (transposed conv outs), V[c][m]        (bf16)
//   Tt[n][m] = sum_c Kt[m][c] Qt[n][c]                        (bf16, raw scores)
//   softmax over n per m:  stats fused into k_qk epilogue -> partial (M,S)
//   c[m] = exp(-M)/S  (k_stats2 merges 32 partials)
//   k_pv: O[c][n] = sum_m V[c][m] * (exp(Tt[n][m]) * c[m])    (exp in staging)
//   out = relu(gamma*O + resid)
// All GEMMs: bf16 MFMA 16x16x32, 128x128 block tile, 4 waves of 64x64.
// ---------------------------------------------------------------------------

typedef __attribute__((ext_vector_type(8))) __bf16 bf16x8;
typedef __attribute__((ext_vector_type(4))) float f32x4;
typedef __attribute__((ext_vector_type(4))) unsigned short us4;

#define LDS_STRIDE 40  // 32 + 8 pad: keeps 16B alignment, 2-way conflicts only

__device__ __forceinline__ unsigned short f2bf(float f) {
  union { float f; unsigned u; } v; v.f = f;
  unsigned r = v.u + 0x7FFFu + ((v.u >> 16) & 1u);
  return (unsigned short)(r >> 16);
}
__device__ __forceinline__ float bf2f(unsigned short b) {
  union { unsigned u; float f; } v; v.u = ((unsigned)b) << 16;
  return v.f;
}

// Core: C[128x128 at (rowbase,colbase)] += A[row][k] * B[col][k]^T
// A: [rows][K] row-major (lda), B: [cols][K] row-major (ldb) -- both K-contig.
// EXPB: element-wise transform B <- bf16(exp(B) * cscale[k]) during staging.
template <bool EXPB>
__device__ __forceinline__ void gemm_core(
    const unsigned short* __restrict__ Ag, const unsigned short* __restrict__ Bg,
    int K, int lda, int ldb, int rowbase, int colbase,
    const float* __restrict__ cscale,
    f32x4 (&acc)[4][4], unsigned short* Al, unsigned short* Bl) {
  const int tid = threadIdx.x;
  const int w = tid >> 6, lane = tid & 63;
  const int quad = lane >> 4, l16 = lane & 15;
  const int wm = (w >> 1) << 6, wn = (w & 1) << 6;

  for (int k0 = 0; k0 < K; k0 += 32) {
#pragma unroll
    for (int t = 0; t < 2; ++t) {
      int cid = (t << 8) + tid;
      int row = cid >> 2;
      int kc = (cid & 3) << 3;
      *(int4*)(Al + row * LDS_STRIDE + kc) =
          *(const int4*)(Ag + (size_t)(rowbase + row) * lda + (k0 + kc));
      int4 raw = *(const int4*)(Bg + (size_t)(colbase + row) * ldb + (k0 + kc));
      if (EXPB) {
        unsigned short* u = (unsigned short*)&raw;
        float4 c0 = *(const float4*)(cscale + k0 + kc);
        float4 c1 = *(const float4*)(cscale + k0 + kc + 4);
        u[0] = f2bf(__expf(bf2f(u[0])) * c0.x);
        u[1] = f2bf(__expf(bf2f(u[1])) * c0.y);
        u[2] = f2bf(__expf(bf2f(u[2])) * c0.z);
        u[3] = f2bf(__expf(bf2f(u[3])) * c0.w);
        u[4] = f2bf(__expf(bf2f(u[4])) * c1.x);
        u[5] = f2bf(__expf(bf2f(u[5])) * c1.y);
        u[6] = f2bf(__expf(bf2f(u[6])) * c1.z);
        u[7] = f2bf(__expf(bf2f(u[7])) * c1.w);
      }
      *(int4*)(Bl + row * LDS_STRIDE + kc) = raw;
    }
    __syncthreads();
    bf16x8 af[4], bfr[4];
#pragma unroll
    for (int i = 0; i < 4; ++i)
      af[i] = *(const bf16x8*)(Al + (wm + (i << 4) + l16) * LDS_STRIDE + (quad << 3));
#pragma unroll
    for (int j = 0; j < 4; ++j)
      bfr[j] = *(const bf16x8*)(Bl + (wn + (j << 4) + l16) * LDS_STRIDE + (quad << 3));
#pragma unroll
    for (int i = 0; i < 4; ++i)
#pragma unroll
      for (int j = 0; j < 4; ++j)
        acc[i][j] = __builtin_amdgcn_mfma_f32_16x16x32_bf16(af[i], bfr[j], acc[i][j], 0, 0, 0);
    __syncthreads();
  }
}

// ---------------- weight fp32 -> bf16 -----------------------------------
struct WArgs { const float* src[6]; unsigned short* dst[6]; };
__global__ __launch_bounds__(256) void k_cvtw(WArgs a) {
  int z = blockIdx.y;
  int i = blockIdx.x * 256 + threadIdx.x;
  a.dst[z][i] = f2bf(a.src[z][i]);
}

// ---------------- transpose+convert: x[b][c][n] f32 -> Xt[b][n][c] bf16 --
struct TArgs { const float* src[4]; unsigned short* dst[4]; };
__global__ __launch_bounds__(256) void k_tcvt(TArgs a) {
  __shared__ float tile[32][33];
  const float* src = a.src[blockIdx.z];
  unsigned short* dst = a.dst[blockIdx.z];
  int n0 = blockIdx.x << 5;   // spatial
  int r0 = blockIdx.y << 5;   // global row = b*512 + c
  int tx = threadIdx.x & 31, ty = threadIdx.x >> 5;  // 32 x 8
#pragma unroll
  for (int i = 0; i < 4; ++i)
    tile[ty * 4 + i][tx] = src[(size_t)(r0 + ty * 4 + i) * 4096 + n0 + tx];
  __syncthreads();
  int b = r0 >> 9, c0 = r0 & 511;
#pragma unroll
  for (int i = 0; i < 4; ++i) {
    int nn = ty * 4 + i;
    dst[(size_t)b * (4096 * 512) + (size_t)(n0 + nn) * 512 + c0 + tx] =
        f2bf(tile[tx][nn]);
  }
}

// ---------------- conv1x1 GEMMs: Y[o][n] = W[o][c] Xt[n][c]^T + bias -----
struct ConvArgs {
  const unsigned short* W[12];
  const unsigned short* X[12];
  const float* bias[12];
  unsigned short* out[12];
  int trans[12];  // 1: store out[n][o] (Q,K) ; 0: store out[o][n] (V)
};
__global__ __launch_bounds__(256) void k_conv(ConvArgs a) {
  __shared__ unsigned short Al[128 * LDS_STRIDE], Bl[128 * LDS_STRIDE];
  int z = blockIdx.z;
  int rowbase = blockIdx.y << 7, colbase = blockIdx.x << 7;
  f32x4 acc[4][4];
#pragma unroll
  for (int i = 0; i < 4; ++i)
#pragma unroll
    for (int j = 0; j < 4; ++j) acc[i][j] = (f32x4){0.f, 0.f, 0.f, 0.f};
  gemm_core<false>(a.W[z], a.X[z], 512, 512, 512, rowbase, colbase, nullptr, acc, Al, Bl);

  const int tid = threadIdx.x, w = tid >> 6, lane = tid & 63;
  const int quad = lane >> 4, l16 = lane & 15;
  const int wm = (w >> 1) << 6, wn = (w & 1) << 6;
  const float* bias = a.bias[z];
  unsigned short* out = a.out[z];
  if (a.trans[z]) {
#pragma unroll
    for (int i = 0; i < 4; ++i) {
      int o0 = rowbase + wm + (i << 4) + (quad << 2);
      float b0 = bias[o0], b1 = bias[o0 + 1], b2 = bias[o0 + 2], b3 = bias[o0 + 3];
#pragma unroll
      for (int j = 0; j < 4; ++j) {
        int n = colbase + wn + (j << 4) + l16;
        us4 v;
        v.x = f2bf(acc[i][j].x + b0);
        v.y = f2bf(acc[i][j].y + b1);
        v.z = f2bf(acc[i][j].z + b2);
        v.w = f2bf(acc[i][j].w + b3);
        *(us4*)(out + (size_t)n * 512 + o0) = v;
      }
    }
  } else {
#pragma unroll
    for (int i = 0; i < 4; ++i) {
      int o0 = rowbase + wm + (i << 4) + (quad << 2);
      float b0 = bias[o0], b1 = bias[o0 + 1], b2 = bias[o0 + 2], b3 = bias[o0 + 3];
#pragma unroll
      for (int j = 0; j < 4; ++j) {
        int n = colbase + wn + (j << 4) + l16;
        out[(size_t)(o0 + 0) * 4096 + n] = f2bf(acc[i][j].x + b0);
        out[(size_t)(o0 + 1) * 4096 + n] = f2bf(acc[i][j].y + b1);
        out[(size_t)(o0 + 2) * 4096 + n] = f2bf(acc[i][j].z + b2);
        out[(size_t)(o0 + 3) * 4096 + n] = f2bf(acc[i][j].w + b3);
      }
    }
  }
}

// ---------------- T = K^T Q : Tt[n][m] bf16, fused partial softmax stats --
// Partial (max, sum-exp) over this block's 128 n values, per m row.
struct QKArgs {
  const unsigned short* A[4]; const unsigned short* B[4]; unsigned short* T[4];
  float* pmx; float* pz;  // [4 z][32 nblk][4096 m]
};
__global__ __launch_bounds__(256) void k_qk(QKArgs a) {
  __shared__ unsigned short Al[128 * LDS_STRIDE], Bl[128 * LDS_STRIDE];
  int z = blockIdx.z;
  int rowbase = blockIdx.y << 7;  // m
  int colbase = blockIdx.x << 7;  // n
  f32x4 acc[4][4];
#pragma unroll
  for (int i = 0; i < 4; ++i)
#pragma unroll
    for (int j = 0; j < 4; ++j) acc[i][j] = (f32x4){0.f, 0.f, 0.f, 0.f};
  gemm_core<false>(a.A[z], a.B[z], 512, 512, 512, rowbase, colbase, nullptr, acc, Al, Bl);

  const int tid = threadIdx.x, w = tid >> 6, lane = tid & 63;
  const int quad = lane >> 4, l16 = lane & 15;
  const int wm = (w >> 1) << 6, wn = (w & 1) << 6;
  unsigned short* T = a.T[z];
  // Store bf16 T and replace acc with the bf16-rounded values (so the stats
  // match exactly what k_pv will re-exponentiate).
#pragma unroll
  for (int i = 0; i < 4; ++i) {
    int m0 = rowbase + wm + (i << 4) + (quad << 2);
#pragma unroll
    for (int j = 0; j < 4; ++j) {
      int n = colbase + wn + (j << 4) + l16;
      us4 v;
      v.x = f2bf(acc[i][j].x);
      v.y = f2bf(acc[i][j].y);
      v.z = f2bf(acc[i][j].z);
      v.w = f2bf(acc[i][j].w);
      *(us4*)(T + (size_t)n * 4096 + m0) = v;
      acc[i][j].x = bf2f(v.x);
      acc[i][j].y = bf2f(v.y);
      acc[i][j].z = bf2f(v.z);
      acc[i][j].w = bf2f(v.w);
    }
  }
  // Per-m (row) max & sum-exp over the 128 n values of this block.
  // Row m maps to (i, quad, r) fixed; its n values live across j x l16 (one
  // wave, 64 vals) and the paired wave with the other wn (other 64).
  float* red = (float*)Al;  // [4 waves][64 rows][2] = 2 KB, reuse LDS
#pragma unroll
  for (int i = 0; i < 4; ++i) {
#pragma unroll
    for (int r = 0; r < 4; ++r) {
      float lmax = fmaxf(fmaxf(acc[i][0][r], acc[i][1][r]),
                         fmaxf(acc[i][2][r], acc[i][3][r]));
#pragma unroll
      for (int d = 1; d < 16; d <<= 1) lmax = fmaxf(lmax, __shfl_xor(lmax, d, 64));
      float ls = 0.f;
#pragma unroll
      for (int j = 0; j < 4; ++j) ls += __expf(acc[i][j][r] - lmax);
#pragma unroll
      for (int d = 1; d < 16; d <<= 1) ls += __shfl_xor(ls, d, 64);
      if (l16 == 0) {
        int lr = (i << 4) + (quad << 2) + r;  // 0..63 within wm half
        red[((w << 6) + lr) * 2 + 0] = lmax;
        red[((w << 6) + lr) * 2 + 1] = ls;
      }
    }
  }
  __syncthreads();
  if (tid < 128) {
    int wmh = tid >> 6, lr = tid & 63;
    float M0 = red[(((wmh << 1) + 0) * 64 + lr) * 2 + 0];
    float S0 = red[(((wmh << 1) + 0) * 64 + lr) * 2 + 1];
    float M1 = red[(((wmh << 1) + 1) * 64 + lr) * 2 + 0];
    float S1 = red[(((wmh << 1) + 1) * 64 + lr) * 2 + 1];
    float M = fmaxf(M0, M1);
    float S = S0 * __expf(M0 - M) + S1 * __expf(M1 - M);
    int m = rowbase + (wmh << 6) + lr;
    int idx = ((z << 5) + blockIdx.x) * 4096 + m;
    a.pmx[idx] = M;
    a.pz[idx] = S;
  }
}

// ---------------- merge 32 partials -> c[m] = exp(-M)/S ------------------
__global__ __launch_bounds__(256) void k_stats2(const float* __restrict__ pmx,
                                                const float* __restrict__ pz,
                                                float* __restrict__ c) {
  int m = (blockIdx.x << 8) + threadIdx.x;
  int z = blockIdx.y;
  float M = -1e30f;
#pragma unroll
  for (int k = 0; k < 32; ++k) M = fmaxf(M, pmx[((z << 5) + k) * 4096 + m]);
  float S = 0.f;
#pragma unroll
  for (int k = 0; k < 32; ++k)
    S += pz[((z << 5) + k) * 4096 + m] * __expf(pmx[((z << 5) + k) * 4096 + m] - M);
  c[z * 4096 + m] = __expf(-M) / S;
}

// ---------------- O = V * exp(T)*c, epilogue relu(gamma*O + resid) -------
struct PVArgs {
  const unsigned short* V[4];
  const unsigned short* P[4];  // raw scores Tt[n][m]
  const float* resid[4];
  const float* gamma[4];
  float* out[4];
  const float* c;  // [4 z][4096 m]
};
__global__ __launch_bounds__(256) void k_pv(PVArgs a) {
  __shared__ unsigned short Al[128 * LDS_STRIDE], Bl[128 * LDS_STRIDE];
  int z = blockIdx.z;
  int rowbase = blockIdx.y << 7;  // c
  int colbase = blockIdx.x << 7;  // n
  f32x4 acc[4][4];
#pragma unroll
  for (int i = 0; i < 4; ++i)
#pragma unroll
    for (int j = 0; j < 4; ++j) acc[i][j] = (f32x4){0.f, 0.f, 0.f, 0.f};
  gemm_core<true>(a.V[z], a.P[z], 4096, 4096, 4096, rowbase, colbase,
                  a.c + z * 4096, acc, Al, Bl);

  const int tid = threadIdx.x, w = tid >> 6, lane = tid & 63;
  const int quad = lane >> 4, l16 = lane & 15;
  const int wm = (w >> 1) << 6, wn = (w & 1) << 6;
  float g = a.gamma[z][0];
  const float* R = a.resid[z];
  float* O = a.out[z];
#pragma unroll
  for (int i = 0; i < 4; ++i) {
    int c0 = rowbase + wm + (i << 4) + (quad << 2);
#pragma unroll
    for (int j = 0; j < 4; ++j) {
      int n = colbase + wn + (j << 4) + l16;
      O[(size_t)(c0 + 0) * 4096 + n] = fmaxf(g * acc[i][j].x + R[(size_t)(c0 + 0) * 4096 + n], 0.f);
      O[(size_t)(c0 + 1) * 4096 + n] = fmaxf(g * acc[i][j].y + R[(size_t)(c0 + 1) * 4096 + n], 0.f);
      O[(size_t)(c0 + 2) * 4096 + n] = fmaxf(g * acc[i][j].z + R[(size_t)(c0 + 2) * 4096 + n], 0.f);
      O[(size_t)(c0 + 3) * 4096 + n] = fmaxf(g * acc[i][j].w + R[(size_t)(c0 + 3) * 4096 + n], 0.f);
    }
  }
}

// ---------------------------------------------------------------------------
extern "C" void kernel_launch(void* const* d_in, const int* in_sizes, int n_in,
                              void* d_out, int out_size, void* d_ws, size_t ws_size,
                              hipStream_t stream) {
  char* ws = (char*)d_ws;
  // workspace layout (bytes):
  unsigned short* wb  = (unsigned short*)(ws);              //  6 x 512x512 bf16 =   3,145,728
  unsigned short* xt  = (unsigned short*)(ws + 3145728);    //  4 x [2][4096][512] =33,554,432
  unsigned short* qkv = (unsigned short*)(ws + 36700160);   // 12 x [4096x512]   = 50,331,648
  unsigned short* tt  = (unsigned short*)(ws + 87031808);   //  4 x [4096x4096]  =134,217,728
  // stats overlap the xt region (xt is dead after k_conv):
  float* pmx = (float*)(ws + 3145728);                      // 4*32*4096 f32 = 2 MB
  float* pz  = (float*)(ws + 3145728 + 2097152);            // 2 MB
  float* cb  = (float*)(ws + 3145728 + 4194304);            // 4*4096 f32 = 64 KB
  // total = 221,249,536 B (< round-1's verified 222.4 MB)

  // 1. weights -> bf16
  WArgs wa;
  for (int i = 0; i < 6; ++i) {
    wa.src[i] = (const float*)d_in[4 + 2 * i];
    wa.dst[i] = wb + (size_t)i * 262144;
  }
  k_cvtw<<<dim3(1024, 6), 256, 0, stream>>>(wa);

  // 2. feature maps -> transposed bf16 Xt[b][n][c]
  TArgs ta;
  for (int ai = 0; ai < 4; ++ai) {
    ta.src[ai] = (const float*)d_in[ai];
    ta.dst[ai] = xt + (size_t)ai * 4194304;
  }
  k_tcvt<<<dim3(128, 32, 4), 256, 0, stream>>>(ta);

  // 3. six convs x two batches (q_rd, k_rd, v_rd, q_dr, k_dr, v_dr)
  const int srcArr[6] = {2, 0, 3, 3, 1, 1};  // x_vis_p, visSegF, x_ir_p, x_ir_p, irSegF, irSegF
  const int trans[6] = {1, 1, 0, 1, 1, 0};   // Q,K transposed; V normal
  ConvArgs ca;
  for (int ci = 0; ci < 6; ++ci)
    for (int b = 0; b < 2; ++b) {
      int zz = ci * 2 + b;
      ca.W[zz] = wb + (size_t)ci * 262144;
      ca.X[zz] = xt + (size_t)srcArr[ci] * 4194304 + (size_t)b * 2097152;
      ca.bias[zz] = (const float*)d_in[5 + 2 * ci];
      ca.out[zz] = qkv + (size_t)zz * 2097152;
      ca.trans[zz] = trans[ci];
    }
  k_conv<<<dim3(32, 4, 12), 256, 0, stream>>>(ca);

  // 4. Tt[n][m] = K^T Q + fused partial softmax stats (z = path*2 + b)
  QKArgs qa;
  for (int path = 0; path < 2; ++path)
    for (int b = 0; b < 2; ++b) {
      int zz = path * 2 + b;
      qa.A[zz] = qkv + (size_t)((path * 3 + 1) * 2 + b) * 2097152;  // Kt
      qa.B[zz] = qkv + (size_t)((path * 3 + 0) * 2 + b) * 2097152;  // Qt
      qa.T[zz] = tt + (size_t)zz * 16777216;
    }
  qa.pmx = pmx;
  qa.pz = pz;
  k_qk<<<dim3(32, 32, 4), 256, 0, stream>>>(qa);

  // 5. merge partials -> c[m]
  k_stats2<<<dim3(16, 4), 256, 0, stream>>>(pmx, pz, cb);

  // 6. O = V P (P formed on the fly) + fused epilogue
  PVArgs pa;
  const float* resid_src[2] = {(const float*)d_in[2], (const float*)d_in[3]};
  const float* gsrc[2] = {(const float*)d_in[16], (const float*)d_in[17]};
  for (int path = 0; path < 2; ++path)
    for (int b = 0; b < 2; ++b) {
      int zz = path * 2 + b;
      pa.V[zz] = qkv + (size_t)((path * 3 + 2) * 2 + b) * 2097152;
      pa.P[zz] = tt + (size_t)zz * 16777216;
      pa.resid[zz] = resid_src[path] + (size_t)b * 2097152;
      pa.gamma[zz] = gsrc[path];
      pa.out[zz] = (float*)d_out + (size_t)path * 4194304 + (size_t)b * 2097152;
    }
  pa.c = cb;
  k_pv<<<dim3(32, 4, 4), 256, 0, stream>>>(pa);
}

// Round 3
// 442.918 us; speedup vs baseline: 1.4448x; 1.2081x over previous
//
#include <hip/hip_runtime.h>
#include <stdint.h>

// ---------------------------------------------------------------------------
// FeatureMapTransformer: dual cross-attention (rd / dr paths), B=2, C=512,
// H=W=64 -> N=M=4096.
//   Qt[n][c], Kt[m][c] (transposed conv outs), V[c][m]        (bf16)
//   Et[n][m] = bf16(exp(sum_c Kt[m][c] Qt[n][c]))             (k_qk, raw exp)
//   stats (M,S) per m fused into k_qk -> c[m] = exp(-M)/S     (k_stats2)
//   V'[c][m] = V[c][m] * c[m]                                 (k_vscale)
//   O[c][n]  = sum_m V'[c][m] E[n][m]  (pure bf16 GEMM)       (k_pv)
//   out = relu(gamma*O + resid)
// GEMM staging: global_load_lds width-16 (async DMA), XOR chunk swizzle
// c' = c ^ ((row>>1)&3) applied on the GLOBAL address side so fragment
// ds_read_b128 is exactly 2-way bank aliased (free per m136).
// ---------------------------------------------------------------------------

typedef __attribute__((ext_vector_type(8))) __bf16 bf16x8;
typedef __attribute__((ext_vector_type(4))) float f32x4;
typedef __attribute__((ext_vector_type(4))) unsigned short us4;

__device__ __forceinline__ unsigned short f2bf(float f) {
  union { float f; unsigned u; } v; v.f = f;
  unsigned r = v.u + 0x7FFFu + ((v.u >> 16) & 1u);
  return (unsigned short)(r >> 16);
}
__device__ __forceinline__ float bf2f(unsigned short b) {
  union { unsigned u; float f; } v; v.u = ((unsigned)b) << 16;
  return v.f;
}

// async 16B global->LDS copy; LDS dest = wave-uniform base + lane*16
__device__ __forceinline__ void async_copy16(const unsigned short* g,
                                             unsigned short* l) {
  __builtin_amdgcn_global_load_lds(
      (const __attribute__((address_space(1))) unsigned int*)g,
      (__attribute__((address_space(3))) unsigned int*)l, 16, 0, 0);
}

// Core: C[128x128 at (rowbase,colbase)] += A[row][k] * B[col][k]^T
// A: [rows][K] row-major (lda), B: [cols][K] row-major (ldb) -- K-contig.
// LDS tiles: 128 rows x 32 k, unpadded (stride 32 shorts = 64 B), with the
// 16B chunk of row r that holds global k-chunk c stored at slot c^((r>>1)&3).
__device__ __forceinline__ void gemm_core(
    const unsigned short* __restrict__ Ag, const unsigned short* __restrict__ Bg,
    int K, int lda, int ldb, int rowbase, int colbase,
    f32x4 (&acc)[4][4], unsigned short* Al, unsigned short* Bl) {
  const int tid = threadIdx.x;
  const int w = tid >> 6, lane = tid & 63;
  const int quad = lane >> 4, l16 = lane & 15;
  const int wm = (w >> 1) << 6, wn = (w & 1) << 6;

  // staging: per wave, 2 issues x 16 rows each for A and B (64 lanes*16B = 1KB)
  const int rbase = (w << 5) + (lane >> 2);

  for (int k0 = 0; k0 < K; k0 += 32) {
#pragma unroll
    for (int i = 0; i < 2; ++i) {
      int rloc = rbase + (i << 4);
      int cg = (lane & 3) ^ ((rloc >> 1) & 3);  // global chunk for this slot
      int koff = k0 + (cg << 3);
      int ldsoff = ((w << 5) + (i << 4)) << 5;  // row*32 shorts, wave-uniform
      async_copy16(Ag + (size_t)(rowbase + rloc) * lda + koff, Al + ldsoff);
      async_copy16(Bg + (size_t)(colbase + rloc) * ldb + koff, Bl + ldsoff);
    }
    __syncthreads();
    bf16x8 af[4], bfr[4];
#pragma unroll
    for (int i = 0; i < 4; ++i) {
      int r = wm + (i << 4) + l16;
      af[i] = *(const bf16x8*)(Al + (r << 5) + ((quad ^ ((r >> 1) & 3)) << 3));
    }
#pragma unroll
    for (int j = 0; j < 4; ++j) {
      int r = wn + (j << 4) + l16;
      bfr[j] = *(const bf16x8*)(Bl + (r << 5) + ((quad ^ ((r >> 1) & 3)) << 3));
    }
#pragma unroll
    for (int i = 0; i < 4; ++i)
#pragma unroll
      for (int j = 0; j < 4; ++j)
        acc[i][j] = __builtin_amdgcn_mfma_f32_16x16x32_bf16(af[i], bfr[j], acc[i][j], 0, 0, 0);
    __syncthreads();
  }
}

// ---------------- weight fp32 -> bf16 -----------------------------------
struct WArgs { const float* src[6]; unsigned short* dst[6]; };
__global__ __launch_bounds__(256) void k_cvtw(WArgs a) {
  int z = blockIdx.y;
  int i = blockIdx.x * 256 + threadIdx.x;
  a.dst[z][i] = f2bf(a.src[z][i]);
}

// ---------------- transpose+convert: x[b][c][n] f32 -> Xt[b][n][c] bf16 --
struct TArgs { const float* src[4]; unsigned short* dst[4]; };
__global__ __launch_bounds__(256) void k_tcvt(TArgs a) {
  __shared__ float tile[32][33];
  const float* src = a.src[blockIdx.z];
  unsigned short* dst = a.dst[blockIdx.z];
  int n0 = blockIdx.x << 5;   // spatial
  int r0 = blockIdx.y << 5;   // global row = b*512 + c
  int tx = threadIdx.x & 31, ty = threadIdx.x >> 5;  // 32 x 8
#pragma unroll
  for (int i = 0; i < 4; ++i)
    tile[ty * 4 + i][tx] = src[(size_t)(r0 + ty * 4 + i) * 4096 + n0 + tx];
  __syncthreads();
  int b = r0 >> 9, c0 = r0 & 511;
#pragma unroll
  for (int i = 0; i < 4; ++i) {
    int nn = ty * 4 + i;
    dst[(size_t)b * (4096 * 512) + (size_t)(n0 + nn) * 512 + c0 + tx] =
        f2bf(tile[tx][nn]);
  }
}

// ---------------- conv1x1 GEMMs: Y[o][n] = W[o][c] Xt[n][c]^T + bias -----
struct ConvArgs {
  const unsigned short* W[12];
  const unsigned short* X[12];
  const float* bias[12];
  unsigned short* out[12];
  int trans[12];  // 1: store out[n][o] (Q,K) ; 0: store out[o][n] (V)
};
__global__ __launch_bounds__(256) void k_conv(ConvArgs a) {
  __shared__ unsigned short Al[128 * 32], Bl[128 * 32];
  int z = blockIdx.z;
  int rowbase = blockIdx.y << 7, colbase = blockIdx.x << 7;
  f32x4 acc[4][4];
#pragma unroll
  for (int i = 0; i < 4; ++i)
#pragma unroll
    for (int j = 0; j < 4; ++j) acc[i][j] = (f32x4){0.f, 0.f, 0.f, 0.f};
  gemm_core(a.W[z], a.X[z], 512, 512, 512, rowbase, colbase, acc, Al, Bl);

  const int tid = threadIdx.x, w = tid >> 6, lane = tid & 63;
  const int quad = lane >> 4, l16 = lane & 15;
  const int wm = (w >> 1) << 6, wn = (w & 1) << 6;
  const float* bias = a.bias[z];
  unsigned short* out = a.out[z];
  if (a.trans[z]) {
#pragma unroll
    for (int i = 0; i < 4; ++i) {
      int o0 = rowbase + wm + (i << 4) + (quad << 2);
      float b0 = bias[o0], b1 = bias[o0 + 1], b2 = bias[o0 + 2], b3 = bias[o0 + 3];
#pragma unroll
      for (int j = 0; j < 4; ++j) {
        int n = colbase + wn + (j << 4) + l16;
        us4 v;
        v.x = f2bf(acc[i][j].x + b0);
        v.y = f2bf(acc[i][j].y + b1);
        v.z = f2bf(acc[i][j].z + b2);
        v.w = f2bf(acc[i][j].w + b3);
        *(us4*)(out + (size_t)n * 512 + o0) = v;
      }
    }
  } else {
#pragma unroll
    for (int i = 0; i < 4; ++i) {
      int o0 = rowbase + wm + (i << 4) + (quad << 2);
      float b0 = bias[o0], b1 = bias[o0 + 1], b2 = bias[o0 + 2], b3 = bias[o0 + 3];
#pragma unroll
      for (int j = 0; j < 4; ++j) {
        int n = colbase + wn + (j << 4) + l16;
        out[(size_t)(o0 + 0) * 4096 + n] = f2bf(acc[i][j].x + b0);
        out[(size_t)(o0 + 1) * 4096 + n] = f2bf(acc[i][j].y + b1);
        out[(size_t)(o0 + 2) * 4096 + n] = f2bf(acc[i][j].z + b2);
        out[(size_t)(o0 + 3) * 4096 + n] = f2bf(acc[i][j].w + b3);
      }
    }
  }
}

// ---------------- Et[n][m] = exp(K^T Q), fused partial softmax stats -----
struct QKArgs {
  const unsigned short* A[4]; const unsigned short* B[4]; unsigned short* T[4];
  float* pmx; float* pz;  // [4 z][32 nblk][4096 m]
};
__global__ __launch_bounds__(256) void k_qk(QKArgs a) {
  __shared__ unsigned short Al[128 * 32], Bl[128 * 32];
  int z = blockIdx.z;
  int rowbase = blockIdx.y << 7;  // m
  int colbase = blockIdx.x << 7;  // n
  f32x4 acc[4][4];
#pragma unroll
  for (int i = 0; i < 4; ++i)
#pragma unroll
    for (int j = 0; j < 4; ++j) acc[i][j] = (f32x4){0.f, 0.f, 0.f, 0.f};
  gemm_core(a.A[z], a.B[z], 512, 512, 512, rowbase, colbase, acc, Al, Bl);

  const int tid = threadIdx.x, w = tid >> 6, lane = tid & 63;
  const int quad = lane >> 4, l16 = lane & 15;
  const int wm = (w >> 1) << 6, wn = (w & 1) << 6;
  unsigned short* T = a.T[z];
  // store raw exp(T) -- |T| << 88 so no overflow; bf16 covers the range
#pragma unroll
  for (int i = 0; i < 4; ++i) {
    int m0 = rowbase + wm + (i << 4) + (quad << 2);
#pragma unroll
    for (int j = 0; j < 4; ++j) {
      int n = colbase + wn + (j << 4) + l16;
      us4 v;
      v.x = f2bf(__expf(acc[i][j].x));
      v.y = f2bf(__expf(acc[i][j].y));
      v.z = f2bf(__expf(acc[i][j].z));
      v.w = f2bf(__expf(acc[i][j].w));
      *(us4*)(T + (size_t)n * 4096 + m0) = v;
    }
  }
  // per-m (row) max & sum-exp over this block's 128 n values
  float* red = (float*)Al;  // [4 waves][64 rows][2] floats = 2 KB, reuse LDS
#pragma unroll
  for (int i = 0; i < 4; ++i) {
#pragma unroll
    for (int r = 0; r < 4; ++r) {
      float lmax = fmaxf(fmaxf(acc[i][0][r], acc[i][1][r]),
                         fmaxf(acc[i][2][r], acc[i][3][r]));
#pragma unroll
      for (int d = 1; d < 16; d <<= 1) lmax = fmaxf(lmax, __shfl_xor(lmax, d, 64));
      float ls = 0.f;
#pragma unroll
      for (int j = 0; j < 4; ++j) ls += __expf(acc[i][j][r] - lmax);
#pragma unroll
      for (int d = 1; d < 16; d <<= 1) ls += __shfl_xor(ls, d, 64);
      if (l16 == 0) {
        int lr = (i << 4) + (quad << 2) + r;
        red[((w << 6) + lr) * 2 + 0] = lmax;
        red[((w << 6) + lr) * 2 + 1] = ls;
      }
    }
  }
  __syncthreads();
  if (tid < 128) {
    int wmh = tid >> 6, lr = tid & 63;
    float M0 = red[(((wmh << 1) + 0) * 64 + lr) * 2 + 0];
    float S0 = red[(((wmh << 1) + 0) * 64 + lr) * 2 + 1];
    float M1 = red[(((wmh << 1) + 1) * 64 + lr) * 2 + 0];
    float S1 = red[(((wmh << 1) + 1) * 64 + lr) * 2 + 1];
    float M = fmaxf(M0, M1);
    float S = S0 * __expf(M0 - M) + S1 * __expf(M1 - M);
    int m = rowbase + (wmh << 6) + lr;
    int idx = ((z << 5) + blockIdx.x) * 4096 + m;
    a.pmx[idx] = M;
    a.pz[idx] = S;
  }
}

// ---------------- merge 32 partials -> c[m] = exp(-M)/S ------------------
__global__ __launch_bounds__(256) void k_stats2(const float* __restrict__ pmx,
                                                const float* __restrict__ pz,
                                                float* __restrict__ c) {
  int m = (blockIdx.x << 8) + threadIdx.x;
  int z = blockIdx.y;
  float M = -1e30f;
#pragma unroll
  for (int k = 0; k < 32; ++k) M = fmaxf(M, pmx[((z << 5) + k) * 4096 + m]);
  float S = 0.f;
#pragma unroll
  for (int k = 0; k < 32; ++k)
    S += pz[((z << 5) + k) * 4096 + m] * __expf(pmx[((z << 5) + k) * 4096 + m] - M);
  c[z * 4096 + m] = __expf(-M) / S;
}

// ---------------- V'[c][m] = V[c][m] * c[m] (in place) -------------------
struct VSArgs { unsigned short* V[4]; const float* c; };
__global__ __launch_bounds__(256) void k_vscale(VSArgs a) {
  int z = blockIdx.y;
  int t = blockIdx.x * 256 + threadIdx.x;   // 1024 blocks: 512*4096/8 lanes
  int m0 = (t & 511) << 3;
  int row = t >> 9;
  unsigned short* p = a.V[z] + (size_t)row * 4096 + m0;
  const float* cz = a.c + z * 4096 + m0;
  int4 raw = *(const int4*)p;
  unsigned short* u = (unsigned short*)&raw;
#pragma unroll
  for (int j = 0; j < 8; ++j) u[j] = f2bf(bf2f(u[j]) * cz[j]);
  *(int4*)p = raw;
}

// ---------------- O = V' E, epilogue relu(gamma*O + resid) ---------------
struct PVArgs {
  const unsigned short* V[4];
  const unsigned short* P[4];  // Et[n][m]
  const float* resid[4];
  const float* gamma[4];
  float* out[4];
};
__global__ __launch_bounds__(256) void k_pv(PVArgs a) {
  __shared__ unsigned short Al[128 * 32], Bl[128 * 32];
  int z = blockIdx.z;
  int rowbase = blockIdx.y << 7;  // c
  int colbase = blockIdx.x << 7;  // n
  f32x4 acc[4][4];
#pragma unroll
  for (int i = 0; i < 4; ++i)
#pragma unroll
    for (int j = 0; j < 4; ++j) acc[i][j] = (f32x4){0.f, 0.f, 0.f, 0.f};
  gemm_core(a.V[z], a.P[z], 4096, 4096, 4096, rowbase, colbase, acc, Al, Bl);

  const int tid = threadIdx.x, w = tid >> 6, lane = tid & 63;
  const int quad = lane >> 4, l16 = lane & 15;
  const int wm = (w >> 1) << 6, wn = (w & 1) << 6;
  float g = a.gamma[z][0];
  const float* R = a.resid[z];
  float* O = a.out[z];
#pragma unroll
  for (int i = 0; i < 4; ++i) {
    int c0 = rowbase + wm + (i << 4) + (quad << 2);
#pragma unroll
    for (int j = 0; j < 4; ++j) {
      int n = colbase + wn + (j << 4) + l16;
      O[(size_t)(c0 + 0) * 4096 + n] = fmaxf(g * acc[i][j].x + R[(size_t)(c0 + 0) * 4096 + n], 0.f);
      O[(size_t)(c0 + 1) * 4096 + n] = fmaxf(g * acc[i][j].y + R[(size_t)(c0 + 1) * 4096 + n], 0.f);
      O[(size_t)(c0 + 2) * 4096 + n] = fmaxf(g * acc[i][j].z + R[(size_t)(c0 + 2) * 4096 + n], 0.f);
      O[(size_t)(c0 + 3) * 4096 + n] = fmaxf(g * acc[i][j].w + R[(size_t)(c0 + 3) * 4096 + n], 0.f);
    }
  }
}

// ---------------------------------------------------------------------------
extern "C" void kernel_launch(void* const* d_in, const int* in_sizes, int n_in,
                              void* d_out, int out_size, void* d_ws, size_t ws_size,
                              hipStream_t stream) {
  char* ws = (char*)d_ws;
  unsigned short* wb  = (unsigned short*)(ws);              //  6 x 512x512 bf16
  unsigned short* xt  = (unsigned short*)(ws + 3145728);    //  4 x [2][4096][512]
  unsigned short* qkv = (unsigned short*)(ws + 36700160);   // 12 x [4096x512]
  unsigned short* tt  = (unsigned short*)(ws + 87031808);   //  4 x [4096x4096]
  // stats overlap the xt region (xt dead after k_conv):
  float* pmx = (float*)(ws + 3145728);                      // 4*32*4096 f32
  float* pz  = (float*)(ws + 3145728 + 2097152);
  float* cb  = (float*)(ws + 3145728 + 4194304);            // 4*4096 f32

  // 1. weights -> bf16
  WArgs wa;
  for (int i = 0; i < 6; ++i) {
    wa.src[i] = (const float*)d_in[4 + 2 * i];
    wa.dst[i] = wb + (size_t)i * 262144;
  }
  k_cvtw<<<dim3(1024, 6), 256, 0, stream>>>(wa);

  // 2. feature maps -> transposed bf16 Xt[b][n][c]
  TArgs ta;
  for (int ai = 0; ai < 4; ++ai) {
    ta.src[ai] = (const float*)d_in[ai];
    ta.dst[ai] = xt + (size_t)ai * 4194304;
  }
  k_tcvt<<<dim3(128, 32, 4), 256, 0, stream>>>(ta);

  // 3. six convs x two batches (q_rd, k_rd, v_rd, q_dr, k_dr, v_dr)
  const int srcArr[6] = {2, 0, 3, 3, 1, 1};
  const int trans[6] = {1, 1, 0, 1, 1, 0};
  ConvArgs ca;
  for (int ci = 0; ci < 6; ++ci)
    for (int b = 0; b < 2; ++b) {
      int zz = ci * 2 + b;
      ca.W[zz] = wb + (size_t)ci * 262144;
      ca.X[zz] = xt + (size_t)srcArr[ci] * 4194304 + (size_t)b * 2097152;
      ca.bias[zz] = (const float*)d_in[5 + 2 * ci];
      ca.out[zz] = qkv + (size_t)zz * 2097152;
      ca.trans[zz] = trans[ci];
    }
  k_conv<<<dim3(32, 4, 12), 256, 0, stream>>>(ca);

  // 4. Et[n][m] = exp(K^T Q) + fused partial stats
  QKArgs qa;
  for (int path = 0; path < 2; ++path)
    for (int b = 0; b < 2; ++b) {
      int zz = path * 2 + b;
      qa.A[zz] = qkv + (size_t)((path * 3 + 1) * 2 + b) * 2097152;  // Kt
      qa.B[zz] = qkv + (size_t)((path * 3 + 0) * 2 + b) * 2097152;  // Qt
      qa.T[zz] = tt + (size_t)zz * 16777216;
    }
  qa.pmx = pmx;
  qa.pz = pz;
  k_qk<<<dim3(32, 32, 4), 256, 0, stream>>>(qa);

  // 5. merge partials -> c[m]
  k_stats2<<<dim3(16, 4), 256, 0, stream>>>(pmx, pz, cb);

  // 6. V' = V * c[m]
  VSArgs va;
  for (int path = 0; path < 2; ++path)
    for (int b = 0; b < 2; ++b)
      va.V[path * 2 + b] = qkv + (size_t)((path * 3 + 2) * 2 + b) * 2097152;
  va.c = cb;
  k_vscale<<<dim3(1024, 4), 256, 0, stream>>>(va);

  // 7. O = V' E + fused epilogue (pure bf16 GEMM)
  PVArgs pa;
  const float* resid_src[2] = {(const float*)d_in[2], (const float*)d_in[3]};
  const float* gsrc[2] = {(const float*)d_in[16], (const float*)d_in[17]};
  for (int path = 0; path < 2; ++path)
    for (int b = 0; b < 2; ++b) {
      int zz = path * 2 + b;
      pa.V[zz] = qkv + (size_t)((path * 3 + 2) * 2 + b) * 2097152;
      pa.P[zz] = tt + (size_t)zz * 16777216;
      pa.resid[zz] = resid_src[path] + (size_t)b * 2097152;
      pa.gamma[zz] = gsrc[path];
      pa.out[zz] = (float*)d_out + (size_t)path * 4194304 + (size_t)b * 2097152;
    }
  k_pv<<<dim3(32, 4, 4), 256, 0, stream>>>(pa);
}

// Round 5
// 424.560 us; speedup vs baseline: 1.5073x; 1.0432x over previous
//
#include <hip/hip_runtime.h>
#include <stdint.h>

// ---------------------------------------------------------------------------
// FeatureMapTransformer: dual cross-attention (rd / dr paths), B=2, C=512,
// H=W=64 -> N=M=4096.
//   Qt[n][c], Kt[m][c] (transposed conv outs), V[c][m]        (bf16)
//   Et[n][m] = bf16(exp(sum_c Kt[m][c] Qt[n][c]))             (k_qk, raw exp)
//   partial S[m] = sum_n exp(T) fused into k_qk (no max pass: |T| <~ 30,
//   exp fits fp32 easily) -> c[m] = 1/S                       (k_stats2)
//   V'[c][m] = V[c][m] * c[m]                                 (k_vscale)
//   O[c][n]  = sum_m V'[c][m] E[n][m]  (pure bf16 GEMM)       (k_pv)
//   out = relu(gamma*O + resid)
// GEMM staging: global_load_lds width-16 (async DMA), BK=64 as two 32-k
// sub-tiles (4096 shorts each -- ROUND-4 BUG WAS half<<13, must be half<<12)
// staged before one barrier pair. XOR chunk swizzle c' = c ^ ((row>>1)&3)
// on the GLOBAL address side keeps fragment ds_read_b128 at 2-way bank
// aliasing (free per m136).
// ---------------------------------------------------------------------------

typedef __attribute__((ext_vector_type(8))) __bf16 bf16x8;
typedef __attribute__((ext_vector_type(4))) float f32x4;
typedef __attribute__((ext_vector_type(4))) unsigned short us4;

__device__ __forceinline__ unsigned short f2bf(float f) {
  union { float f; unsigned u; } v; v.f = f;
  unsigned r = v.u + 0x7FFFu + ((v.u >> 16) & 1u);
  return (unsigned short)(r >> 16);
}
__device__ __forceinline__ float bf2f(unsigned short b) {
  union { unsigned u; float f; } v; v.u = ((unsigned)b) << 16;
  return v.f;
}

// async 16B global->LDS copy; LDS dest = wave-uniform base + lane*16
__device__ __forceinline__ void async_copy16(const unsigned short* g,
                                             unsigned short* l) {
  __builtin_amdgcn_global_load_lds(
      (const __attribute__((address_space(1))) unsigned int*)g,
      (__attribute__((address_space(3))) unsigned int*)l, 16, 0, 0);
}

// Core: C[128x128 at (rowbase,colbase)] += A[row][k] * B[col][k]^T
// A: [rows][K] row-major (lda), B: [cols][K] row-major (ldb) -- K-contig.
// Al/Bl: each TWO 128x32 sub-tiles (4096 shorts apart), unpadded stride 32
// shorts; 16B chunk c of row r lives at slot c^((r>>1)&3).
__device__ __forceinline__ void gemm_core(
    const unsigned short* __restrict__ Ag, const unsigned short* __restrict__ Bg,
    int K, int lda, int ldb, int rowbase, int colbase,
    f32x4 (&acc)[4][4], unsigned short* Al, unsigned short* Bl) {
  const int tid = threadIdx.x;
  const int w = tid >> 6, lane = tid & 63;
  const int quad = lane >> 4, l16 = lane & 15;
  const int wm = (w >> 1) << 6, wn = (w & 1) << 6;
  const int rbase = (w << 5) + (lane >> 2);

  for (int k0 = 0; k0 < K; k0 += 64) {
    // stage both 32-k sub-tiles before one barrier (16 issues in flight)
#pragma unroll
    for (int half = 0; half < 2; ++half) {
      int kh = k0 + (half << 5);
      unsigned short* Ah = Al + (half << 12);  // 4096 shorts per sub-tile
      unsigned short* Bh = Bl + (half << 12);
#pragma unroll
      for (int i = 0; i < 2; ++i) {
        int rloc = rbase + (i << 4);
        int cg = (lane & 3) ^ ((rloc >> 1) & 3);
        int koff = kh + (cg << 3);
        int ldsoff = ((w << 5) + (i << 4)) << 5;  // row*32 shorts, wave-uniform
        async_copy16(Ag + (size_t)(rowbase + rloc) * lda + koff, Ah + ldsoff);
        async_copy16(Bg + (size_t)(colbase + rloc) * ldb + koff, Bh + ldsoff);
      }
    }
    __syncthreads();
#pragma unroll
    for (int half = 0; half < 2; ++half) {
      unsigned short* Ah = Al + (half << 12);
      unsigned short* Bh = Bl + (half << 12);
      bf16x8 af[4], bfr[4];
#pragma unroll
      for (int i = 0; i < 4; ++i) {
        int r = wm + (i << 4) + l16;
        af[i] = *(const bf16x8*)(Ah + (r << 5) + ((quad ^ ((r >> 1) & 3)) << 3));
      }
#pragma unroll
      for (int j = 0; j < 4; ++j) {
        int r = wn + (j << 4) + l16;
        bfr[j] = *(const bf16x8*)(Bh + (r << 5) + ((quad ^ ((r >> 1) & 3)) << 3));
      }
#pragma unroll
      for (int i = 0; i < 4; ++i)
#pragma unroll
        for (int j = 0; j < 4; ++j)
          acc[i][j] = __builtin_amdgcn_mfma_f32_16x16x32_bf16(af[i], bfr[j], acc[i][j], 0, 0, 0);
    }
    __syncthreads();
  }
}

// ---------------- weight fp32 -> bf16 -----------------------------------
struct WArgs { const float* src[6]; unsigned short* dst[6]; };
__global__ __launch_bounds__(256) void k_cvtw(WArgs a) {
  int z = blockIdx.y;
  int i = blockIdx.x * 256 + threadIdx.x;
  a.dst[z][i] = f2bf(a.src[z][i]);
}

// ---------------- transpose+convert: x[b][c][n] f32 -> Xt[b][n][c] bf16 --
struct TArgs { const float* src[4]; unsigned short* dst[4]; };
__global__ __launch_bounds__(256) void k_tcvt(TArgs a) {
  __shared__ float tile[32][33];
  const float* src = a.src[blockIdx.z];
  unsigned short* dst = a.dst[blockIdx.z];
  int n0 = blockIdx.x << 5;   // spatial
  int r0 = blockIdx.y << 5;   // global row = b*512 + c
  int tx = threadIdx.x & 31, ty = threadIdx.x >> 5;  // 32 x 8
#pragma unroll
  for (int i = 0; i < 4; ++i)
    tile[ty * 4 + i][tx] = src[(size_t)(r0 + ty * 4 + i) * 4096 + n0 + tx];
  __syncthreads();
  int b = r0 >> 9, c0 = r0 & 511;
#pragma unroll
  for (int i = 0; i < 4; ++i) {
    int nn = ty * 4 + i;
    dst[(size_t)b * (4096 * 512) + (size_t)(n0 + nn) * 512 + c0 + tx] =
        f2bf(tile[tx][nn]);
  }
}

// ---------------- conv1x1 GEMMs: Y[o][n] = W[o][c] Xt[n][c]^T + bias -----
struct ConvArgs {
  const unsigned short* W[12];
  const unsigned short* X[12];
  const float* bias[12];
  unsigned short* out[12];
  int trans[12];  // 1: store out[n][o] (Q,K) ; 0: store out[o][n] (V)
};
__global__ __launch_bounds__(256) void k_conv(ConvArgs a) {
  __shared__ unsigned short Al[2 * 128 * 32], Bl[2 * 128 * 32];
  int z = blockIdx.z;
  int rowbase = blockIdx.y << 7, colbase = blockIdx.x << 7;
  f32x4 acc[4][4];
#pragma unroll
  for (int i = 0; i < 4; ++i)
#pragma unroll
    for (int j = 0; j < 4; ++j) acc[i][j] = (f32x4){0.f, 0.f, 0.f, 0.f};
  gemm_core(a.W[z], a.X[z], 512, 512, 512, rowbase, colbase, acc, Al, Bl);

  const int tid = threadIdx.x, w = tid >> 6, lane = tid & 63;
  const int quad = lane >> 4, l16 = lane & 15;
  const int wm = (w >> 1) << 6, wn = (w & 1) << 6;
  const float* bias = a.bias[z];
  unsigned short* out = a.out[z];
  if (a.trans[z]) {
#pragma unroll
    for (int i = 0; i < 4; ++i) {
      int o0 = rowbase + wm + (i << 4) + (quad << 2);
      float b0 = bias[o0], b1 = bias[o0 + 1], b2 = bias[o0 + 2], b3 = bias[o0 + 3];
#pragma unroll
      for (int j = 0; j < 4; ++j) {
        int n = colbase + wn + (j << 4) + l16;
        us4 v;
        v.x = f2bf(acc[i][j].x + b0);
        v.y = f2bf(acc[i][j].y + b1);
        v.z = f2bf(acc[i][j].z + b2);
        v.w = f2bf(acc[i][j].w + b3);
        *(us4*)(out + (size_t)n * 512 + o0) = v;
      }
    }
  } else {
#pragma unroll
    for (int i = 0; i < 4; ++i) {
      int o0 = rowbase + wm + (i << 4) + (quad << 2);
      float b0 = bias[o0], b1 = bias[o0 + 1], b2 = bias[o0 + 2], b3 = bias[o0 + 3];
#pragma unroll
      for (int j = 0; j < 4; ++j) {
        int n = colbase + wn + (j << 4) + l16;
        out[(size_t)(o0 + 0) * 4096 + n] = f2bf(acc[i][j].x + b0);
        out[(size_t)(o0 + 1) * 4096 + n] = f2bf(acc[i][j].y + b1);
        out[(size_t)(o0 + 2) * 4096 + n] = f2bf(acc[i][j].z + b2);
        out[(size_t)(o0 + 3) * 4096 + n] = f2bf(acc[i][j].w + b3);
      }
    }
  }
}

// ---------------- Et[n][m] = exp(K^T Q), fused partial sum S[m] ----------
struct QKArgs {
  const unsigned short* A[4]; const unsigned short* B[4]; unsigned short* T[4];
  float* pz;  // [4 z][32 nblk][4096 m] partial sums
};
__global__ __launch_bounds__(256) void k_qk(QKArgs a) {
  __shared__ unsigned short Al[2 * 128 * 32], Bl[2 * 128 * 32];
  int z = blockIdx.z;
  int rowbase = blockIdx.y << 7;  // m
  int colbase = blockIdx.x << 7;  // n
  f32x4 acc[4][4];
#pragma unroll
  for (int i = 0; i < 4; ++i)
#pragma unroll
    for (int j = 0; j < 4; ++j) acc[i][j] = (f32x4){0.f, 0.f, 0.f, 0.f};
  gemm_core(a.A[z], a.B[z], 512, 512, 512, rowbase, colbase, acc, Al, Bl);

  const int tid = threadIdx.x, w = tid >> 6, lane = tid & 63;
  const int quad = lane >> 4, l16 = lane & 15;
  const int wm = (w >> 1) << 6, wn = (w & 1) << 6;
  unsigned short* T = a.T[z];
  float* red = (float*)Al;  // [4 waves][64 rows] partial sums, reuse LDS
  // store raw exp(T) (|T| << 88) and accumulate row sums
#pragma unroll
  for (int i = 0; i < 4; ++i) {
    int m0 = rowbase + wm + (i << 4) + (quad << 2);
    float rs0 = 0.f, rs1 = 0.f, rs2 = 0.f, rs3 = 0.f;
#pragma unroll
    for (int j = 0; j < 4; ++j) {
      int n = colbase + wn + (j << 4) + l16;
      float e0 = __expf(acc[i][j].x);
      float e1 = __expf(acc[i][j].y);
      float e2 = __expf(acc[i][j].z);
      float e3 = __expf(acc[i][j].w);
      us4 v;
      v.x = f2bf(e0); v.y = f2bf(e1); v.z = f2bf(e2); v.w = f2bf(e3);
      *(us4*)(T + (size_t)n * 4096 + m0) = v;
      rs0 += e0; rs1 += e1; rs2 += e2; rs3 += e3;
    }
#pragma unroll
    for (int d = 1; d < 16; d <<= 1) {
      rs0 += __shfl_xor(rs0, d, 64);
      rs1 += __shfl_xor(rs1, d, 64);
      rs2 += __shfl_xor(rs2, d, 64);
      rs3 += __shfl_xor(rs3, d, 64);
    }
    if (l16 == 0) {
      int lr = (i << 4) + (quad << 2);  // local row within wm half
      red[(w << 6) + lr + 0] = rs0;
      red[(w << 6) + lr + 1] = rs1;
      red[(w << 6) + lr + 2] = rs2;
      red[(w << 6) + lr + 3] = rs3;
    }
  }
  __syncthreads();
  if (tid < 128) {
    int h = tid >> 6, lr = tid & 63;  // wm half, local row
    float S = red[((h << 1) << 6) + lr] + red[(((h << 1) + 1) << 6) + lr];
    int m = rowbase + (h << 6) + lr;
    a.pz[((z << 5) + blockIdx.x) * 4096 + m] = S;
  }
}

// ---------------- merge 32 partials -> c[m] = 1/S ------------------------
__global__ __launch_bounds__(256) void k_stats2(const float* __restrict__ pz,
                                                float* __restrict__ c) {
  int m = (blockIdx.x << 8) + threadIdx.x;
  int z = blockIdx.y;
  float S = 0.f;
#pragma unroll
  for (int k = 0; k < 32; ++k) S += pz[((z << 5) + k) * 4096 + m];
  c[z * 4096 + m] = 1.f / S;
}

// ---------------- V'[c][m] = V[c][m] * c[m] (in place) -------------------
struct VSArgs { unsigned short* V[4]; const float* c; };
__global__ __launch_bounds__(256) void k_vscale(VSArgs a) {
  int z = blockIdx.y;
  int t = blockIdx.x * 256 + threadIdx.x;
  int m0 = (t & 511) << 3;
  int row = t >> 9;
  unsigned short* p = a.V[z] + (size_t)row * 4096 + m0;
  const float* cz = a.c + z * 4096 + m0;
  int4 raw = *(const int4*)p;
  unsigned short* u = (unsigned short*)&raw;
#pragma unroll
  for (int j = 0; j < 8; ++j) u[j] = f2bf(bf2f(u[j]) * cz[j]);
  *(int4*)p = raw;
}

// ---------------- O = V' E, epilogue relu(gamma*O + resid) ---------------
struct PVArgs {
  const unsigned short* V[4];
  const unsigned short* P[4];  // Et[n][m]
  const float* resid[4];
  const float* gamma[4];
  float* out[4];
};
__global__ __launch_bounds__(256) void k_pv(PVArgs a) {
  __shared__ unsigned short Al[2 * 128 * 32], Bl[2 * 128 * 32];
  int z = blockIdx.z;
  int rowbase = blockIdx.y << 7;  // c
  int colbase = blockIdx.x << 7;  // n
  f32x4 acc[4][4];
#pragma unroll
  for (int i = 0; i < 4; ++i)
#pragma unroll
    for (int j = 0; j < 4; ++j) acc[i][j] = (f32x4){0.f, 0.f, 0.f, 0.f};
  gemm_core(a.V[z], a.P[z], 4096, 4096, 4096, rowbase, colbase, acc, Al, Bl);

  const int tid = threadIdx.x, w = tid >> 6, lane = tid & 63;
  const int quad = lane >> 4, l16 = lane & 15;
  const int wm = (w >> 1) << 6, wn = (w & 1) << 6;
  float g = a.gamma[z][0];
  const float* R = a.resid[z];
  float* O = a.out[z];
#pragma unroll
  for (int i = 0; i < 4; ++i) {
    int c0 = rowbase + wm + (i << 4) + (quad << 2);
#pragma unroll
    for (int j = 0; j < 4; ++j) {
      int n = colbase + wn + (j << 4) + l16;
      O[(size_t)(c0 + 0) * 4096 + n] = fmaxf(g * acc[i][j].x + R[(size_t)(c0 + 0) * 4096 + n], 0.f);
      O[(size_t)(c0 + 1) * 4096 + n] = fmaxf(g * acc[i][j].y + R[(size_t)(c0 + 1) * 4096 + n], 0.f);
      O[(size_t)(c0 + 2) * 4096 + n] = fmaxf(g * acc[i][j].z + R[(size_t)(c0 + 2) * 4096 + n], 0.f);
      O[(size_t)(c0 + 3) * 4096 + n] = fmaxf(g * acc[i][j].w + R[(size_t)(c0 + 3) * 4096 + n], 0.f);
    }
  }
}

// ---------------------------------------------------------------------------
extern "C" void kernel_launch(void* const* d_in, const int* in_sizes, int n_in,
                              void* d_out, int out_size, void* d_ws, size_t ws_size,
                              hipStream_t stream) {
  char* ws = (char*)d_ws;
  unsigned short* wb  = (unsigned short*)(ws);              //  6 x 512x512 bf16
  unsigned short* xt  = (unsigned short*)(ws + 3145728);    //  4 x [2][4096][512]
  unsigned short* qkv = (unsigned short*)(ws + 36700160);   // 12 x [4096x512]
  unsigned short* tt  = (unsigned short*)(ws + 87031808);   //  4 x [4096x4096]
  // stats overlap the xt region (xt dead after k_conv):
  float* pz  = (float*)(ws + 3145728);                      // 4*32*4096 f32
  float* cb  = (float*)(ws + 3145728 + 2097152);            // 4*4096 f32

  // 1. weights -> bf16
  WArgs wa;
  for (int i = 0; i < 6; ++i) {
    wa.src[i] = (const float*)d_in[4 + 2 * i];
    wa.dst[i] = wb + (size_t)i * 262144;
  }
  k_cvtw<<<dim3(1024, 6), 256, 0, stream>>>(wa);

  // 2. feature maps -> transposed bf16 Xt[b][n][c]
  TArgs ta;
  for (int ai = 0; ai < 4; ++ai) {
    ta.src[ai] = (const float*)d_in[ai];
    ta.dst[ai] = xt + (size_t)ai * 4194304;
  }
  k_tcvt<<<dim3(128, 32, 4), 256, 0, stream>>>(ta);

  // 3. six convs x two batches (q_rd, k_rd, v_rd, q_dr, k_dr, v_dr)
  const int srcArr[6] = {2, 0, 3, 3, 1, 1};
  const int trans[6] = {1, 1, 0, 1, 1, 0};
  ConvArgs ca;
  for (int ci = 0; ci < 6; ++ci)
    for (int b = 0; b < 2; ++b) {
      int zz = ci * 2 + b;
      ca.W[zz] = wb + (size_t)ci * 262144;
      ca.X[zz] = xt + (size_t)srcArr[ci] * 4194304 + (size_t)b * 2097152;
      ca.bias[zz] = (const float*)d_in[5 + 2 * ci];
      ca.out[zz] = qkv + (size_t)zz * 2097152;
      ca.trans[zz] = trans[ci];
    }
  k_conv<<<dim3(32, 4, 12), 256, 0, stream>>>(ca);

  // 4. Et[n][m] = exp(K^T Q) + fused partial sums
  QKArgs qa;
  for (int path = 0; path < 2; ++path)
    for (int b = 0; b < 2; ++b) {
      int zz = path * 2 + b;
      qa.A[zz] = qkv + (size_t)((path * 3 + 1) * 2 + b) * 2097152;  // Kt
      qa.B[zz] = qkv + (size_t)((path * 3 + 0) * 2 + b) * 2097152;  // Qt
      qa.T[zz] = tt + (size_t)zz * 16777216;
    }
  qa.pz = pz;
  k_qk<<<dim3(32, 32, 4), 256, 0, stream>>>(qa);

  // 5. merge partials -> c[m] = 1/S
  k_stats2<<<dim3(16, 4), 256, 0, stream>>>(pz, cb);

  // 6. V' = V * c[m]
  VSArgs va;
  for (int path = 0; path < 2; ++path)
    for (int b = 0; b < 2; ++b)
      va.V[path * 2 + b] = qkv + (size_t)((path * 3 + 2) * 2 + b) * 2097152;
  va.c = cb;
  k_vscale<<<dim3(1024, 4), 256, 0, stream>>>(va);

  // 7. O = V' E + fused epilogue (pure bf16 GEMM)
  PVArgs pa;
  const float* resid_src[2] = {(const float*)d_in[2], (const float*)d_in[3]};
  const float* gsrc[2] = {(const float*)d_in[16], (const float*)d_in[17]};
  for (int path = 0; path < 2; ++path)
    for (int b = 0; b < 2; ++b) {
      int zz = path * 2 + b;
      pa.V[zz] = qkv + (size_t)((path * 3 + 2) * 2 + b) * 2097152;
      pa.P[zz] = tt + (size_t)zz * 16777216;
      pa.resid[zz] = resid_src[path] + (size_t)b * 2097152;
      pa.gamma[zz] = gsrc[path];
      pa.out[zz] = (float*)d_out + (size_t)path * 4194304 + (size_t)b * 2097152;
    }
  k_pv<<<dim3(32, 4, 4), 256, 0, stream>>>(pa);
}